// Round 1
// baseline (596.895 us; speedup 1.0000x reference)
//
#include <hip/hip_runtime.h>

// ----------------------------------------------------------------------------
// S4 block: y = GELU( irfft(rfft(u,2L) * (rfft(k,2L) + D)) [:L] ) ; out = W@y + b
// B=8, C=1, H=512, L=8192, N=2L=16384
//
// Pipeline:
//   k0 wconv       : W fp32 -> bf16 (ws)
//   k1 kf_build    : per h, DIF-FFT(16384) of k row, +D[h] on every bin, store
//                    scrambled spectrum Kf (ws, fp32 complex)
//   k2 conv_gelu   : per (h, batch-pair): pack z=u_b0+i*u_b1, DIF-FFT, multiply
//                    by Kf (scrambled), DIT-IFFT, scale, GELU, store g bf16
//                    (g lives in d_out's tail-unused bytes -> first 64MB)
//   kT transpose_g : g[b][h][l] -> gT[b][l][h] (bf16) so GEMM B-frags are
//                    K-contiguous
//   k3 gemm_out    : out[b,o,l] = sum_d Wb[o,d]*gT[b,l,d] + bias[o]
//                    128x128x(K=32) tile, mfma_f32_16x16x32_bf16, 4 waves
// ----------------------------------------------------------------------------

typedef unsigned short ushort_t;
typedef __bf16 bf16x8 __attribute__((ext_vector_type(8)));
typedef float  f32x4  __attribute__((ext_vector_type(4)));

// LDS index map: +1 complex pad every 16 to break power-of-2 stride conflicts
__device__ __forceinline__ int phi_idx(int p) { return p + (p >> 4); }

__device__ __forceinline__ float2 cmulf(float2 a, float2 b) {
    return make_float2(a.x * b.x - a.y * b.y, a.x * b.y + a.y * b.x);
}
__device__ __forceinline__ float2 caddf(float2 a, float2 b) { return make_float2(a.x + b.x, a.y + b.y); }
__device__ __forceinline__ float2 csubf(float2 a, float2 b) { return make_float2(a.x - b.x, a.y - b.y); }

__device__ __forceinline__ ushort_t f2bf(float f) {
    unsigned int u = __float_as_uint(f);
    u = (u + 0x7fffu + ((u >> 16) & 1u)) >> 16;
    return (ushort_t)u;
}

__device__ __forceinline__ float gelu_exact(float x) {
    return 0.5f * x * (1.0f + erff(x * 0.70710678118654752f));
}

// ---------------- forward DIF radix-4, N=16384, in-place, scrambled output ---
// 1024 threads; Z accessed through phi_idx. syncthreads at top of each stage.
__device__ void fft16384_dif(float2* Z, int tid)
{
    for (int stage = 0; stage < 7; ++stage) {
        int log2m = 12 - 2 * stage;
        int m  = 1 << log2m;
        int n4 = m << 2;
        float ang0 = -6.283185307179586f / (float)n4;
        __syncthreads();
#pragma unroll
        for (int r = 0; r < 4; ++r) {
            int idx  = tid + (r << 10);
            int j    = idx & (m - 1);
            int grp  = idx >> log2m;
            int base = grp * n4 + j;
            float2 a = Z[phi_idx(base)];
            float2 b = Z[phi_idx(base + m)];
            float2 c = Z[phi_idx(base + 2 * m)];
            float2 d = Z[phi_idx(base + 3 * m)];
            float2 t0 = caddf(a, c), t1 = csubf(a, c);
            float2 t2 = caddf(b, d), t3 = csubf(b, d);
            float2 o0 = caddf(t0, t2);
            float2 o1 = make_float2(t1.x + t3.y, t1.y - t3.x);   // t1 - i*t3
            float2 o2 = csubf(t0, t2);
            float2 o3 = make_float2(t1.x - t3.y, t1.y + t3.x);   // t1 + i*t3
            if (m > 1) {
                float s, cs;
                __sincosf(ang0 * (float)j, &s, &cs);
                float2 w1 = make_float2(cs, s);       // e^{-i*2pi*j/n}
                float2 w2 = cmulf(w1, w1);
                float2 w3 = cmulf(w2, w1);
                o1 = cmulf(o1, w1);
                o2 = cmulf(o2, w2);
                o3 = cmulf(o3, w3);
            }
            Z[phi_idx(base)]         = o0;
            Z[phi_idx(base + m)]     = o1;
            Z[phi_idx(base + 2 * m)] = o2;
            Z[phi_idx(base + 3 * m)] = o3;
        }
    }
}

// ---------------- inverse DIT radix-4 (scrambled input -> natural), no 1/N ---
__device__ void fft16384_dit_inv(float2* Z, int tid)
{
    for (int stage = 0; stage < 7; ++stage) {
        int log2m = 2 * stage;             // m = 1,4,...,4096
        int m  = 1 << log2m;
        int n4 = m << 2;
        float ang0 = 6.283185307179586f / (float)n4;
        __syncthreads();
#pragma unroll
        for (int r = 0; r < 4; ++r) {
            int idx  = tid + (r << 10);
            int j    = idx & (m - 1);
            int grp  = idx >> log2m;
            int base = grp * n4 + j;
            float2 s0 = Z[phi_idx(base)];
            float2 s1 = Z[phi_idx(base + m)];
            float2 s2 = Z[phi_idx(base + 2 * m)];
            float2 s3 = Z[phi_idx(base + 3 * m)];
            if (m > 1) {
                float s, cs;
                __sincosf(ang0 * (float)j, &s, &cs);
                float2 v1 = make_float2(cs, s);       // e^{+i*2pi*j/n}
                float2 v2 = cmulf(v1, v1);
                float2 v3 = cmulf(v2, v1);
                s1 = cmulf(s1, v1);
                s2 = cmulf(s2, v2);
                s3 = cmulf(s3, v3);
            }
            float2 e0 = caddf(s0, s2), e1 = csubf(s0, s2);
            float2 e2 = caddf(s1, s3), e3 = csubf(s1, s3);
            Z[phi_idx(base)]         = caddf(e0, e2);
            Z[phi_idx(base + m)]     = make_float2(e1.x - e3.y, e1.y + e3.x); // e1 + i*e3
            Z[phi_idx(base + 2 * m)] = csubf(e0, e2);
            Z[phi_idx(base + 3 * m)] = make_float2(e1.x + e3.y, e1.y - e3.x); // e1 - i*e3
        }
    }
}

// ---------------- k0: W fp32 -> bf16 ----------------------------------------
__global__ void wconv(const float* __restrict__ W, ushort_t* __restrict__ Wb, int n)
{
    int i = blockIdx.x * 256 + threadIdx.x;
    if (i < n) Wb[i] = f2bf(W[i]);
}

// ---------------- k1: Kf[h][p] = scrambledFFT(k[h]) + D[h] ------------------
__global__ __launch_bounds__(1024, 1) void kf_build(const float* __restrict__ k,
                                                    const float* __restrict__ D,
                                                    float2* __restrict__ Kf)
{
    __shared__ float2 Z[17408];   // 16384 + pads = 139,264 B
    int h   = blockIdx.x;
    int tid = threadIdx.x;
    const float* kr = k + (size_t)h * 8192;
#pragma unroll
    for (int i = 0; i < 2; ++i) {
        int c = tid + (i << 10);
        float4 v = ((const float4*)kr)[c];
        int p = c * 4;
        Z[phi_idx(p + 0)] = make_float2(v.x, 0.f);
        Z[phi_idx(p + 1)] = make_float2(v.y, 0.f);
        Z[phi_idx(p + 2)] = make_float2(v.z, 0.f);
        Z[phi_idx(p + 3)] = make_float2(v.w, 0.f);
    }
#pragma unroll
    for (int i = 0; i < 8; ++i) {
        int p = 8192 + tid + (i << 10);
        Z[phi_idx(p)] = make_float2(0.f, 0.f);
    }
    fft16384_dif(Z, tid);
    __syncthreads();
    float dh = D[h];                      // C=1: D[0][h]
    float2* outp = Kf + (size_t)h * 16384;
#pragma unroll
    for (int i = 0; i < 16; ++i) {
        int p = tid + (i << 10);
        float2 z = Z[phi_idx(p)];
        z.x += dh;                        // FFT(D*delta) = D on every bin
        outp[p] = z;
    }
}

// ---------------- k2: conv + D-skip + GELU -> g bf16 ------------------------
__global__ __launch_bounds__(1024, 1) void conv_gelu(const float* __restrict__ u,
                                                     const float2* __restrict__ Kf,
                                                     ushort_t* __restrict__ g)
{
    __shared__ float2 Z[17408];
    int h    = blockIdx.x;         // 512
    int pair = blockIdx.y;         // 4
    int b0   = pair * 2;
    int tid  = threadIdx.x;
    const float* u0 = u + ((size_t)(b0 * 512 + h)) * 8192;
    const float* u1 = u0 + (size_t)512 * 8192;
#pragma unroll
    for (int i = 0; i < 2; ++i) {
        int c = tid + (i << 10);
        float4 a = ((const float4*)u0)[c];
        float4 b = ((const float4*)u1)[c];
        int p = c * 4;
        Z[phi_idx(p + 0)] = make_float2(a.x, b.x);
        Z[phi_idx(p + 1)] = make_float2(a.y, b.y);
        Z[phi_idx(p + 2)] = make_float2(a.z, b.z);
        Z[phi_idx(p + 3)] = make_float2(a.w, b.w);
    }
#pragma unroll
    for (int i = 0; i < 8; ++i) {
        int p = 8192 + tid + (i << 10);
        Z[phi_idx(p)] = make_float2(0.f, 0.f);
    }
    fft16384_dif(Z, tid);
    __syncthreads();
    const float2* kf = Kf + (size_t)h * 16384;
#pragma unroll
    for (int i = 0; i < 16; ++i) {
        int p = tid + (i << 10);
        Z[phi_idx(p)] = cmulf(Z[phi_idx(p)], kf[p]);   // same scrambled order
    }
    fft16384_dit_inv(Z, tid);
    __syncthreads();
    const float sc = 1.0f / 16384.0f;
    ushort_t* g0 = g + ((size_t)(b0 * 512 + h)) * 8192;
    ushort_t* g1 = g0 + (size_t)512 * 8192;
#pragma unroll
    for (int i = 0; i < 8; ++i) {
        int p = tid + (i << 10);
        float2 zy = Z[phi_idx(p)];
        g0[p] = f2bf(gelu_exact(zy.x * sc));   // batch b0
        g1[p] = f2bf(gelu_exact(zy.y * sc));   // batch b0+1
    }
}

// ---------------- kT: g[b][h][l] -> gT[b][l][h] -----------------------------
__global__ __launch_bounds__(256) void transpose_g(const ushort_t* __restrict__ g,
                                                   ushort_t* __restrict__ gT)
{
    __shared__ ushort_t TL[64][68];   // [l][h], padded
    int lt = blockIdx.x;   // 128 l-tiles of 64
    int ht = blockIdx.y;   // 8 h-tiles of 64
    int b  = blockIdx.z;   // 8
    int t  = threadIdx.x;
    int l0 = lt * 64, h0 = ht * 64;
#pragma unroll
    for (int i = 0; i < 4; ++i) {
        int c   = t + (i << 8);        // 0..1023 ushort4-chunks
        int row = c >> 4;              // h-row 0..63
        int col = (c & 15) * 4;        // l-col
        const ushort_t* src = g + ((size_t)(b * 512 + h0 + row)) * 8192 + l0 + col;
        ushort4 v = *(const ushort4*)src;
        TL[col + 0][row] = v.x;
        TL[col + 1][row] = v.y;
        TL[col + 2][row] = v.z;
        TL[col + 3][row] = v.w;
    }
    __syncthreads();
#pragma unroll
    for (int i = 0; i < 4; ++i) {
        int c    = t + (i << 8);
        int lrow = c >> 4;
        int hcol = (c & 15) * 4;
        ushort4 v = *(const ushort4*)&TL[lrow][hcol];
        *(ushort4*)(gT + ((size_t)b * 8192 + l0 + lrow) * 512 + h0 + hcol) = v;
    }
}

// ---------------- k3: out[b,o,l] = sum_d Wb[o,d]*gT[b,l,d] + bias[o] --------
__global__ __launch_bounds__(256, 2) void gemm_out(const ushort_t* __restrict__ Wb,
                                                   const ushort_t* __restrict__ gT,
                                                   const float* __restrict__ bias,
                                                   float* __restrict__ out)
{
    __shared__ __align__(16) ushort_t As[128 * 32];  // [o][k]
    __shared__ __align__(16) ushort_t Bs[128 * 32];  // [l][k]
    int lt = blockIdx.x;   // 64 l-tiles
    int ot = blockIdx.y;   // 4 o-tiles
    int b  = blockIdx.z;   // 8
    int l0 = lt * 128, o0 = ot * 128;
    int t    = threadIdx.x;
    int wave = t >> 6, lid = t & 63;
    int wm = wave >> 1, wn = wave & 1;
    int q  = lid >> 4, mi = lid & 15;

    f32x4 acc[4][4];
#pragma unroll
    for (int i = 0; i < 4; ++i)
#pragma unroll
        for (int j = 0; j < 4; ++j)
            acc[i][j] = (f32x4){0.f, 0.f, 0.f, 0.f};

    const size_t gTb = (size_t)b * 8192 * 512;
    for (int it = 0; it < 16; ++it) {
        int k0 = it * 32;
        __syncthreads();
#pragma unroll
        for (int i = 0; i < 2; ++i) {
            int ch  = t + (i << 8);          // 0..511 16B-chunks
            int row = ch >> 2;
            int kc  = (ch & 3) << 3;
            uint4 va = *(const uint4*)(Wb + (size_t)(o0 + row) * 512 + k0 + kc);
            *(uint4*)&As[row * 32 + kc] = va;
            uint4 vb = *(const uint4*)(gT + gTb + (size_t)(l0 + row) * 512 + k0 + kc);
            *(uint4*)&Bs[row * 32 + kc] = vb;
        }
        __syncthreads();
        bf16x8 af[4], bfr[4];
#pragma unroll
        for (int f = 0; f < 4; ++f) {
            af[f]  = *(const bf16x8*)&As[(wm * 64 + f * 16 + mi) * 32 + q * 8];
            bfr[f] = *(const bf16x8*)&Bs[(wn * 64 + f * 16 + mi) * 32 + q * 8];
        }
#pragma unroll
        for (int i = 0; i < 4; ++i)
#pragma unroll
            for (int j = 0; j < 4; ++j)
                acc[i][j] = __builtin_amdgcn_mfma_f32_16x16x32_bf16(af[i], bfr[j], acc[i][j], 0, 0, 0);
    }

#pragma unroll
    for (int i = 0; i < 4; ++i) {
        int o_base = o0 + wm * 64 + i * 16 + q * 4;
#pragma unroll
        for (int j = 0; j < 4; ++j) {
            int l = l0 + wn * 64 + j * 16 + mi;
#pragma unroll
            for (int r = 0; r < 4; ++r) {
                int o = o_base + r;
                out[((size_t)b * 512 + o) * 8192 + l] = acc[i][j][r] + bias[o];
            }
        }
    }
}

// ----------------------------------------------------------------------------
extern "C" void kernel_launch(void* const* d_in, const int* in_sizes, int n_in,
                              void* d_out, int out_size, void* d_ws, size_t ws_size,
                              hipStream_t stream)
{
    (void)in_sizes; (void)n_in; (void)out_size; (void)ws_size;
    const float* u    = (const float*)d_in[0];   // (8,512,8192)
    const float* k    = (const float*)d_in[1];   // (1,512,8192)
    const float* D    = (const float*)d_in[2];   // (1,512)
    const float* W    = (const float*)d_in[3];   // (512,512)
    const float* bias = (const float*)d_in[4];   // (512,)
    float* out = (float*)d_out;

    char* ws = (char*)d_ws;
    float2*   Kf = (float2*)ws;                          // 512*16384*8 = 64 MB
    ushort_t* gT = (ushort_t*)(ws + 67108864);           // 64 MB
    ushort_t* Wb = (ushort_t*)(ws + 134217728);          // 512 KB
    ushort_t* g  = (ushort_t*)d_out;                     // 64 MB staged in out buf

    wconv<<<1024, 256, 0, stream>>>(W, Wb, 512 * 512);
    kf_build<<<512, 1024, 0, stream>>>(k, D, Kf);
    conv_gelu<<<dim3(512, 4), 1024, 0, stream>>>(u, Kf, g);
    transpose_g<<<dim3(128, 8, 8), 256, 0, stream>>>(g, gT);
    gemm_out<<<dim3(64, 4, 8), 256, 0, stream>>>(Wb, gT, bias, out);
}

// Round 2
// 546.410 us; speedup vs baseline: 1.0924x; 1.0924x over previous
//
#include <hip/hip_runtime.h>

// ----------------------------------------------------------------------------
// S4 block: y = GELU( irfft(rfft(u,2L) * (rfft(k,2L) + D)) [:L] ) ; out = W@y + b
// B=8, C=1, H=512, L=8192, N=2L=16384
//
// FFT: four-step register-resident factorization 16384 = 16*16*16*4.
//   1024 threads, 16 complex points/thread in VGPRs. 16-point DFTs with
//   hard-coded twiddles; 3 LDS transposes/pass (pad pi(i)=i+(i>>4): every
//   exchange = 4 lanes/bank = wave64 b64 minimum, conflict-free).
//   Inverse is the exact mirror (conj steps, reverse order).
//   Scrambled bin order sigma is shared by kf_build and conv_gelu, so the
//   pointwise product is order-consistent; D-skip is +D on every bin.
// ----------------------------------------------------------------------------

typedef unsigned short ushort_t;
typedef __bf16 bf16x8 __attribute__((ext_vector_type(8)));
typedef float  f32x4  __attribute__((ext_vector_type(4)));

#define PHI(i) ((i) + ((i) >> 4))
#define TWO_PI 6.283185307179586f

__device__ __forceinline__ float2 cmulf(float2 a, float2 b) {
    return make_float2(a.x * b.x - a.y * b.y, a.x * b.y + a.y * b.x);
}
__device__ __forceinline__ float2 caddf(float2 a, float2 b) { return make_float2(a.x + b.x, a.y + b.y); }
__device__ __forceinline__ float2 csubf(float2 a, float2 b) { return make_float2(a.x - b.x, a.y - b.y); }

__device__ __forceinline__ ushort_t f2bf(float f) {
    unsigned int u = __float_as_uint(f);
    u = (u + 0x7fffu + ((u >> 16) & 1u)) >> 16;
    return (ushort_t)u;
}

__device__ __forceinline__ float gelu_exact(float x) {
    return 0.5f * x * (1.0f + erff(x * 0.70710678118654752f));
}

// ---------------- 4-point DFT, natural in/out (INV = conjugate kernel) ------
template<bool INV>
__device__ __forceinline__ void dft4(float2& x0, float2& x1, float2& x2, float2& x3) {
    float2 t0 = caddf(x0, x2), t1 = csubf(x0, x2);
    float2 t2 = caddf(x1, x3), t3 = csubf(x1, x3);
    x0 = caddf(t0, t2);
    x2 = csubf(t0, t2);
    if (!INV) {
        x1 = make_float2(t1.x + t3.y, t1.y - t3.x);   // t1 - i*t3
        x3 = make_float2(t1.x - t3.y, t1.y + t3.x);   // t1 + i*t3
    } else {
        x1 = make_float2(t1.x - t3.y, t1.y + t3.x);
        x3 = make_float2(t1.x + t3.y, t1.y - t3.x);
    }
}

// multiply by twiddle (wr, wi); INV conjugates the twiddle
template<bool INV>
__device__ __forceinline__ float2 cmulc(float2 a, float wr, float wi) {
    float i2 = INV ? -wi : wi;
    return make_float2(a.x * wr - a.y * i2, a.x * i2 + a.y * wr);
}

#define C1_ 0.9238795325112867f
#define S1_ 0.3826834323650898f
#define R2_ 0.7071067811865476f

// ---------------- 16-point DFT, natural in/out ------------------------------
// four-step 16 = 4x4: n = 4a+b, k = c+4e.
// HZ: inputs r[8..15] are known-zero (skip half the inner butterflies).
template<bool INV, bool HZ>
__device__ __forceinline__ void dft16(float2* r) {
#pragma unroll
    for (int b = 0; b < 4; ++b) {
        if (HZ) {
            float2 u = r[b], v = r[4 + b];
            r[b]     = caddf(u, v);
            r[8 + b] = csubf(u, v);
            if (!INV) { r[4 + b]  = make_float2(u.x + v.y, u.y - v.x);
                        r[12 + b] = make_float2(u.x - v.y, u.y + v.x); }
            else      { r[4 + b]  = make_float2(u.x - v.y, u.y + v.x);
                        r[12 + b] = make_float2(u.x + v.y, u.y - v.x); }
        } else {
            dft4<INV>(r[b], r[4 + b], r[8 + b], r[12 + b]);
        }
    }
    // twiddle r[4c+b] *= w16^{bc}
    r[5]  = cmulc<INV>(r[5],  C1_, -S1_);   // w^1
    r[6]  = cmulc<INV>(r[6],  R2_, -R2_);   // w^2
    r[7]  = cmulc<INV>(r[7],  S1_, -C1_);   // w^3
    r[9]  = cmulc<INV>(r[9],  R2_, -R2_);   // w^2
    r[10] = cmulc<INV>(r[10], 0.f, -1.f);   // w^4
    r[11] = cmulc<INV>(r[11], -R2_, -R2_);  // w^6
    r[13] = cmulc<INV>(r[13], S1_, -C1_);   // w^3
    r[14] = cmulc<INV>(r[14], -R2_, -R2_);  // w^6
    r[15] = cmulc<INV>(r[15], -C1_,  S1_);  // w^9
    float2 o[16];
#pragma unroll
    for (int c = 0; c < 4; ++c) {
        float2 a0 = r[4*c], a1 = r[4*c+1], a2 = r[4*c+2], a3 = r[4*c+3];
        dft4<INV>(a0, a1, a2, a3);
        o[c] = a0; o[c + 4] = a1; o[c + 8] = a2; o[c + 12] = a3;
    }
#pragma unroll
    for (int i = 0; i < 16; ++i) r[i] = o[i];
}

// apply w^k, w = e^{i*theta}, to x[1..15] (x[0] *= w^0)
__device__ __forceinline__ void twiddle_apply(float2* x, float theta) {
    float s, c;
    __sincosf(theta, &s, &c);
    float2 w = make_float2(c, s), wk = w;
#pragma unroll
    for (int k = 1; k < 16; ++k) { x[k] = cmulf(x[k], wk); wk = cmulf(wk, w); }
}

// ---------------- forward: regs(natural a-chunks) -> regs(sigma bins) -------
// thread t holds x[a] = in[a*1024 + t] (a=8..15 zero). Output: 16 sigma-bins.
__device__ __forceinline__ void fft_fwd(float2* x, float2* Z, int t) {
    int k1 = t >> 6, kb = (t >> 2) & 15, f = t & 3, d = t & 63;
    int base = k1 * 1024;
    // phase A: DFT16 over a (half-zero) + twiddle w_N^{k1*t}
    dft16<false, true>(x);
    twiddle_apply(x, -TWO_PI * (float)t * (1.0f / 16384.0f));
    __syncthreads();
#pragma unroll
    for (int r = 0; r < 16; ++r) Z[PHI(r * 1024 + t)] = x[r];
    __syncthreads();
#pragma unroll
    for (int c = 0; c < 16; ++c) x[c] = Z[PHI(base + c * 64 + d)];
    // phase B: DFT16 over c + twiddle w_1024^{k1b*d}
    dft16<false, false>(x);
    twiddle_apply(x, -TWO_PI * (float)d * (1.0f / 1024.0f));
    __syncthreads();
#pragma unroll
    for (int r = 0; r < 16; ++r) Z[PHI(base + r * 64 + d)] = x[r];
    __syncthreads();
#pragma unroll
    for (int e = 0; e < 16; ++e) x[e] = Z[PHI(base + kb * 64 + e * 4 + f)];
    // phase C: DFT16 over e + twiddle w_64^{k1c*f}
    dft16<false, false>(x);
    twiddle_apply(x, -TWO_PI * (float)f * (1.0f / 64.0f));
    __syncthreads();
#pragma unroll
    for (int r = 0; r < 16; ++r) Z[PHI(base + kb * 64 + r * 4 + f)] = x[r];
    __syncthreads();
#pragma unroll
    for (int q = 0; q < 4; ++q)
#pragma unroll
        for (int ff = 0; ff < 4; ++ff)
            x[q * 4 + ff] = Z[PHI(base + kb * 64 + (f * 4 + q) * 4 + ff)];
    // phase D: DFT4 over ff
#pragma unroll
    for (int q = 0; q < 4; ++q) dft4<false>(x[4*q], x[4*q+1], x[4*q+2], x[4*q+3]);
}

// ---------------- inverse: exact mirror; output x[a] = 16384 * time[a*1024+t]
__device__ __forceinline__ void fft_inv(float2* x, float2* Z, int t) {
    int k1 = t >> 6, kb = (t >> 2) & 15, f = t & 3, d = t & 63;
    int base = k1 * 1024;
    // phase D'
#pragma unroll
    for (int q = 0; q < 4; ++q) dft4<true>(x[4*q], x[4*q+1], x[4*q+2], x[4*q+3]);
    __syncthreads();
#pragma unroll
    for (int q = 0; q < 4; ++q)
#pragma unroll
        for (int ff = 0; ff < 4; ++ff)
            Z[PHI(base + kb * 64 + (f * 4 + q) * 4 + ff)] = x[q * 4 + ff];
    __syncthreads();
#pragma unroll
    for (int r = 0; r < 16; ++r) x[r] = Z[PHI(base + kb * 64 + r * 4 + f)];
    // phase C'
    twiddle_apply(x, TWO_PI * (float)f * (1.0f / 64.0f));
    dft16<true, false>(x);
    __syncthreads();
#pragma unroll
    for (int e = 0; e < 16; ++e) Z[PHI(base + kb * 64 + e * 4 + f)] = x[e];
    __syncthreads();
#pragma unroll
    for (int r = 0; r < 16; ++r) x[r] = Z[PHI(base + r * 64 + d)];
    // phase B'
    twiddle_apply(x, TWO_PI * (float)d * (1.0f / 1024.0f));
    dft16<true, false>(x);
    __syncthreads();
#pragma unroll
    for (int c = 0; c < 16; ++c) Z[PHI(base + c * 64 + d)] = x[c];
    __syncthreads();
#pragma unroll
    for (int r = 0; r < 16; ++r) x[r] = Z[PHI(r * 1024 + t)];
    // phase A'
    twiddle_apply(x, TWO_PI * (float)t * (1.0f / 16384.0f));
    dft16<true, false>(x);
}

// ---------------- k0: W fp32 -> bf16 ----------------------------------------
__global__ void wconv(const float* __restrict__ W, ushort_t* __restrict__ Wb, int n)
{
    int i = blockIdx.x * 256 + threadIdx.x;
    if (i < n) Wb[i] = f2bf(W[i]);
}

// ---------------- k1: Kf[h][sigma] = FFT(k[h]) + D[h] -----------------------
__global__ __launch_bounds__(1024, 1) void kf_build(const float* __restrict__ k,
                                                    const float* __restrict__ D,
                                                    float2* __restrict__ Kf)
{
    __shared__ float2 Z[17408];   // PHI(16383)=17406 -> 139,264 B
    int h = blockIdx.x, t = threadIdx.x;
    const float* kr = k + (size_t)h * 8192;
    float2 x[16];
#pragma unroll
    for (int a = 0; a < 8; ++a) x[a] = make_float2(kr[a * 1024 + t], 0.f);
#pragma unroll
    for (int a = 8; a < 16; ++a) x[a] = make_float2(0.f, 0.f);
    fft_fwd(x, Z, t);
    float dh = D[h];
    float2* o = Kf + (size_t)h * 16384;
#pragma unroll
    for (int r = 0; r < 16; ++r) {
        float2 z = x[r];
        z.x += dh;                       // FFT(D*delta) = D on every bin
        o[r * 1024 + t] = z;
    }
}

// ---------------- k2: conv + D-skip + GELU -> g bf16 ------------------------
__global__ __launch_bounds__(1024, 1) void conv_gelu(const float* __restrict__ u,
                                                     const float2* __restrict__ Kf,
                                                     ushort_t* __restrict__ g)
{
    __shared__ float2 Z[17408];
    int h    = blockIdx.x;         // 512
    int pair = blockIdx.y;         // 4
    int b0   = pair * 2;
    int t    = threadIdx.x;
    const float* u0 = u + ((size_t)(b0 * 512 + h)) * 8192;
    const float* u1 = u0 + (size_t)512 * 8192;
    float2 x[16];
#pragma unroll
    for (int a = 0; a < 8; ++a) x[a] = make_float2(u0[a * 1024 + t], u1[a * 1024 + t]);
#pragma unroll
    for (int a = 8; a < 16; ++a) x[a] = make_float2(0.f, 0.f);
    fft_fwd(x, Z, t);
    const float2* kf = Kf + (size_t)blockIdx.x * 16384;
#pragma unroll
    for (int r = 0; r < 16; ++r) x[r] = cmulf(x[r], kf[r * 1024 + t]);
    fft_inv(x, Z, t);
    const float sc = 1.0f / 16384.0f;
    ushort_t* g0 = g + ((size_t)(b0 * 512 + blockIdx.x)) * 8192;
    ushort_t* g1 = g0 + (size_t)512 * 8192;
#pragma unroll
    for (int a = 0; a < 8; ++a) {
        int n = a * 1024 + t;
        g0[n] = f2bf(gelu_exact(x[a].x * sc));   // batch b0
        g1[n] = f2bf(gelu_exact(x[a].y * sc));   // batch b0+1
    }
}

// ---------------- kT: g[b][h][l] -> gT[b][l][h] -----------------------------
__global__ __launch_bounds__(256) void transpose_g(const ushort_t* __restrict__ g,
                                                   ushort_t* __restrict__ gT)
{
    __shared__ ushort_t TL[64][68];   // [l][h], padded
    int lt = blockIdx.x;   // 128 l-tiles of 64
    int ht = blockIdx.y;   // 8 h-tiles of 64
    int b  = blockIdx.z;   // 8
    int t  = threadIdx.x;
    int l0 = lt * 64, h0 = ht * 64;
#pragma unroll
    for (int i = 0; i < 4; ++i) {
        int c   = t + (i << 8);        // 0..1023 ushort4-chunks
        int row = c >> 4;              // h-row 0..63
        int col = (c & 15) * 4;        // l-col
        const ushort_t* src = g + ((size_t)(b * 512 + h0 + row)) * 8192 + l0 + col;
        ushort4 v = *(const ushort4*)src;
        TL[col + 0][row] = v.x;
        TL[col + 1][row] = v.y;
        TL[col + 2][row] = v.z;
        TL[col + 3][row] = v.w;
    }
    __syncthreads();
#pragma unroll
    for (int i = 0; i < 4; ++i) {
        int c    = t + (i << 8);
        int lrow = c >> 4;
        int hcol = (c & 15) * 4;
        ushort4 v = *(const ushort4*)&TL[lrow][hcol];
        *(ushort4*)(gT + ((size_t)b * 8192 + l0 + lrow) * 512 + h0 + hcol) = v;
    }
}

// ---------------- k3: out[b,o,l] = sum_d Wb[o,d]*gT[b,l,d] + bias[o] --------
__global__ __launch_bounds__(256, 2) void gemm_out(const ushort_t* __restrict__ Wb,
                                                   const ushort_t* __restrict__ gT,
                                                   const float* __restrict__ bias,
                                                   float* __restrict__ out)
{
    __shared__ __align__(16) ushort_t As[128 * 32];  // [o][k]
    __shared__ __align__(16) ushort_t Bs[128 * 32];  // [l][k]
    int lt = blockIdx.x;   // 64 l-tiles
    int ot = blockIdx.y;   // 4 o-tiles
    int b  = blockIdx.z;   // 8
    int l0 = lt * 128, o0 = ot * 128;
    int t    = threadIdx.x;
    int wave = t >> 6, lid = t & 63;
    int wm = wave >> 1, wn = wave & 1;
    int q  = lid >> 4, mi = lid & 15;

    f32x4 acc[4][4];
#pragma unroll
    for (int i = 0; i < 4; ++i)
#pragma unroll
        for (int j = 0; j < 4; ++j)
            acc[i][j] = (f32x4){0.f, 0.f, 0.f, 0.f};

    const size_t gTb = (size_t)b * 8192 * 512;
    for (int it = 0; it < 16; ++it) {
        int k0 = it * 32;
        __syncthreads();
#pragma unroll
        for (int i = 0; i < 2; ++i) {
            int ch  = t + (i << 8);          // 0..511 16B-chunks
            int row = ch >> 2;
            int kc  = (ch & 3) << 3;
            uint4 va = *(const uint4*)(Wb + (size_t)(o0 + row) * 512 + k0 + kc);
            *(uint4*)&As[row * 32 + kc] = va;
            uint4 vb = *(const uint4*)(gT + gTb + (size_t)(l0 + row) * 512 + k0 + kc);
            *(uint4*)&Bs[row * 32 + kc] = vb;
        }
        __syncthreads();
        bf16x8 af[4], bfr[4];
#pragma unroll
        for (int ff = 0; ff < 4; ++ff) {
            af[ff]  = *(const bf16x8*)&As[(wm * 64 + ff * 16 + mi) * 32 + q * 8];
            bfr[ff] = *(const bf16x8*)&Bs[(wn * 64 + ff * 16 + mi) * 32 + q * 8];
        }
#pragma unroll
        for (int i = 0; i < 4; ++i)
#pragma unroll
            for (int j = 0; j < 4; ++j)
                acc[i][j] = __builtin_amdgcn_mfma_f32_16x16x32_bf16(af[i], bfr[j], acc[i][j], 0, 0, 0);
    }

#pragma unroll
    for (int i = 0; i < 4; ++i) {
        int o_base = o0 + wm * 64 + i * 16 + q * 4;
#pragma unroll
        for (int j = 0; j < 4; ++j) {
            int l = l0 + wn * 64 + j * 16 + mi;
#pragma unroll
            for (int r = 0; r < 4; ++r) {
                int o = o_base + r;
                out[((size_t)b * 512 + o) * 8192 + l] = acc[i][j][r] + bias[o];
            }
        }
    }
}

// ----------------------------------------------------------------------------
extern "C" void kernel_launch(void* const* d_in, const int* in_sizes, int n_in,
                              void* d_out, int out_size, void* d_ws, size_t ws_size,
                              hipStream_t stream)
{
    (void)in_sizes; (void)n_in; (void)out_size; (void)ws_size;
    const float* u    = (const float*)d_in[0];   // (8,512,8192)
    const float* k    = (const float*)d_in[1];   // (1,512,8192)
    const float* D    = (const float*)d_in[2];   // (1,512)
    const float* W    = (const float*)d_in[3];   // (512,512)
    const float* bias = (const float*)d_in[4];   // (512,)
    float* out = (float*)d_out;

    char* ws = (char*)d_ws;
    float2*   Kf = (float2*)ws;                          // 512*16384*8 = 64 MB
    ushort_t* gT = (ushort_t*)(ws + 67108864);           // 64 MB
    ushort_t* Wb = (ushort_t*)(ws + 134217728);          // 512 KB
    ushort_t* g  = (ushort_t*)d_out;                     // 64 MB staged in out buf

    wconv<<<1024, 256, 0, stream>>>(W, Wb, 512 * 512);
    kf_build<<<512, 1024, 0, stream>>>(k, D, Kf);
    conv_gelu<<<dim3(512, 4), 1024, 0, stream>>>(u, Kf, g);
    transpose_g<<<dim3(128, 8, 8), 256, 0, stream>>>(g, gT);
    gemm_out<<<dim3(64, 4, 8), 256, 0, stream>>>(Wb, gT, bias, out);
}